// Round 2
// baseline (610.883 us; speedup 1.0000x reference)
//
#include <hip/hip_runtime.h>
#include <math.h>

#define N_NODES   262144
#define N_EDGES   4194304
#define NUM_GRAPHS 1024
#define NBIN      1024         // dst buckets (dst >> 8)
#define BNODE     256          // nodes per bucket
#define CAPB      4608         // fixed capacity per bucket (mean 4096, +8 sigma)

static __device__ __forceinline__ float fast_rcp(float v) {
    return __builtin_amdgcn_rcpf(v);
}

// ---------------------------------------------------------------------------
// K0: pack x (4f) + pos (3f) into one 32B record per node -> single 64B line
// per random src gather in the fused kernel.
// ---------------------------------------------------------------------------
__global__ __launch_bounds__(256) void pack_kernel(
    const float* __restrict__ x, const float* __restrict__ pos,
    float* __restrict__ xp)
{
    int n = blockIdx.x * 256 + threadIdx.x;
    float4 xv = *(const float4*)(x + 4*n);
    float px = pos[3*n+0], py = pos[3*n+1], pz = pos[3*n+2];
    float4* o = (float4*)(xp + 8*n);
    o[0] = xv;
    o[1] = make_float4(px, py, pz, 0.0f);
}

// ---------------------------------------------------------------------------
// K1: binning into fixed-stride buckets. 1024 blocks x 256 thr x 16 edges.
// Per-block LDS histogram -> one global cursor atomic per nonzero bin ->
// scatter packed (lo<<18)|src into staged[bin*CAPB + slot].
// No global histogram, no scan, no CSR permute needed.
// ---------------------------------------------------------------------------
__global__ __launch_bounds__(256) void binning_kernel(
    const int* __restrict__ ei, int* __restrict__ cursor,
    int* __restrict__ staged)
{
    __shared__ int cnt[NBIN];
    __shared__ int runbase[NBIN];
    #pragma unroll
    for (int t = 0; t < NBIN/256; ++t) cnt[t*256 + threadIdx.x] = 0;
    __syncthreads();

    int base = blockIdx.x * 4096;
    int ds[16];
    #pragma unroll
    for (int i = 0; i < 16; ++i) {
        ds[i] = ei[N_EDGES + base + i*256 + threadIdx.x];
        atomicAdd(&cnt[ds[i] >> 8], 1);
    }
    __syncthreads();
    #pragma unroll
    for (int t = 0; t < NBIN/256; ++t) {
        int k = t*256 + threadIdx.x;
        int c = cnt[k];
        runbase[k] = c ? atomicAdd(cursor + k, c) : 0;
        cnt[k] = 0;
    }
    __syncthreads();
    #pragma unroll
    for (int i = 0; i < 16; ++i) {
        int e   = base + i*256 + threadIdx.x;
        int src = ei[e];
        int dst = ds[i];
        int bk  = dst >> 8;
        int r   = atomicAdd(&cnt[bk], 1);
        int idx = runbase[bk] + r;
        if (idx < CAPB)                       // ~8-sigma guard, never in practice
            staged[bk*CAPB + idx] = ((dst & 255) << 18) | src;
    }
}

// ---------------------------------------------------------------------------
// K2 (fused): one block per bucket. Edge-parallel over the bucket's unordered
// edge list (perfect load balance), accumulate silu(h) into LDS acc[256][17]
// (stride 17: conflict-free, slot 16 = degree count) via LDS atomics.
// Then per-node epilogue: mean/relu + node MLP + softmax + attention pooling.
// 2-edge unroll: shares each LDS weight read across two edges, keeps two
// random gathers in flight per lane.
// ---------------------------------------------------------------------------
__global__ __launch_bounds__(256, 4) void fused_bucket_kernel(
    const float* __restrict__ xp,
    const int* __restrict__ cursor, const int* __restrict__ staged,
    const int* __restrict__ batch,
    const float* __restrict__ w1, const float* __restrict__ b1,
    const float* __restrict__ w2, const float* __restrict__ b2,
    const float* __restrict__ pw, const float* __restrict__ pb,
    float* __restrict__ s_out, float* __restrict__ pooled)
{
    __shared__ float acc[BNODE * 17];          // 17408 B
    __shared__ __align__(16) float sw1[144];
    __shared__ float sb1[16];
    __shared__ __align__(16) float sw2[256];
    __shared__ float sb2[16];
    __shared__ float spw[32];
    __shared__ float spb[2];

    if (threadIdx.x < 144) sw1[threadIdx.x] = w1[threadIdx.x];
    if (threadIdx.x >= 144 && threadIdx.x < 160) sb1[threadIdx.x - 144] = b1[threadIdx.x - 144];
    if (threadIdx.x >= 160 && threadIdx.x < 176) sb2[threadIdx.x - 160] = b2[threadIdx.x - 160];
    if (threadIdx.x >= 176 && threadIdx.x < 208) spw[threadIdx.x - 176] = pw[threadIdx.x - 176];
    if (threadIdx.x >= 208 && threadIdx.x < 210) spb[threadIdx.x - 208] = pb[threadIdx.x - 208];
    sw2[threadIdx.x] = w2[threadIdx.x];
    #pragma unroll
    for (int t = 0; t < 17; ++t) acc[t*256 + threadIdx.x] = 0.0f;
    __syncthreads();

    int bkt  = blockIdx.x;
    int cnt  = cursor[bkt]; if (cnt > CAPB) cnt = CAPB;
    int base = bkt * CAPB;
    int nb0  = bkt * BNODE;
    const float4* xp4 = (const float4*)xp;

    for (int i = threadIdx.x; i < cnt; i += 512) {
        int iB   = i + 256;
        bool hasB = iB < cnt;
        int pA = staged[base + i];
        int pB = hasB ? staged[base + iB] : pA;

        int srcA = pA & 0x3FFFF, loA = pA >> 18;
        int srcB = pB & 0x3FFFF, loB = pB >> 18;

        float4 xsA = xp4[2*srcA],        psA = xp4[2*srcA + 1];
        float4 xsB = xp4[2*srcB],        psB = xp4[2*srcB + 1];
        float4 xdA = xp4[2*(nb0+loA)],   pdA = xp4[2*(nb0+loA) + 1];
        float4 xdB = xp4[2*(nb0+loB)],   pdB = xp4[2*(nb0+loB) + 1];

        float dxA = psA.x - pdA.x, dyA = psA.y - pdA.y, dzA = psA.z - pdA.z;
        float distA = sqrtf(fmaf(dxA, dxA, fmaf(dyA, dyA, dzA*dzA)));
        float dxB = psB.x - pdB.x, dyB = psB.y - pdB.y, dzB = psB.z - pdB.z;
        float distB = sqrtf(fmaf(dxB, dxB, fmaf(dyB, dyB, dzB*dzB)));

        float featA[9] = {xdA.x, xdA.y, xdA.z, xdA.w, xsA.x, xsA.y, xsA.z, xsA.w, distA};
        float featB[9] = {xdB.x, xdB.y, xdB.z, xdB.w, xsB.x, xsB.y, xsB.z, xsB.w, distB};

        float hA[16], hB[16];
        #pragma unroll
        for (int j = 0; j < 16; ++j) { hA[j] = sb1[j]; hB[j] = sb1[j]; }
        #pragma unroll
        for (int r9 = 0; r9 < 9; ++r9) {
            float fA = featA[r9], fB = featB[r9];
            #pragma unroll
            for (int j4 = 0; j4 < 4; ++j4) {
                float4 w = *(const float4*)&sw1[r9*16 + 4*j4];
                hA[4*j4+0] = fmaf(fA, w.x, hA[4*j4+0]);
                hA[4*j4+1] = fmaf(fA, w.y, hA[4*j4+1]);
                hA[4*j4+2] = fmaf(fA, w.z, hA[4*j4+2]);
                hA[4*j4+3] = fmaf(fA, w.w, hA[4*j4+3]);
                hB[4*j4+0] = fmaf(fB, w.x, hB[4*j4+0]);
                hB[4*j4+1] = fmaf(fB, w.y, hB[4*j4+1]);
                hB[4*j4+2] = fmaf(fB, w.z, hB[4*j4+2]);
                hB[4*j4+3] = fmaf(fB, w.w, hB[4*j4+3]);
            }
        }

        float* aA = &acc[loA * 17];
        #pragma unroll
        for (int j = 0; j < 16; ++j) {
            float s = hA[j] * fast_rcp(1.0f + __expf(-hA[j]));
            atomicAdd(&aA[j], s);
        }
        atomicAdd(&aA[16], 1.0f);
        if (hasB) {
            float* aB = &acc[loB * 17];
            #pragma unroll
            for (int j = 0; j < 16; ++j) {
                float s = hB[j] * fast_rcp(1.0f + __expf(-hB[j]));
                atomicAdd(&aB[j], s);
            }
            atomicAdd(&aB[16], 1.0f);
        }
    }
    __syncthreads();

    // ---- per-node epilogue: n = bkt*256 + tid ----
    int n = nb0 + threadIdx.x;
    const float* a = &acc[threadIdx.x * 17];
    float c   = a[16];
    float inv = fast_rcp(fmaxf(c, 1.0f));

    float h[16];
    #pragma unroll
    for (int j = 0; j < 16; ++j) h[j] = c * sb2[j];
    #pragma unroll
    for (int i = 0; i < 16; ++i) {
        float f = a[i];
        #pragma unroll
        for (int j4 = 0; j4 < 4; ++j4) {
            float4 w = *(const float4*)&sw2[i*16 + 4*j4];
            h[4*j4+0] = fmaf(f, w.x, h[4*j4+0]);
            h[4*j4+1] = fmaf(f, w.y, h[4*j4+1]);
            h[4*j4+2] = fmaf(f, w.z, h[4*j4+2]);
            h[4*j4+3] = fmaf(f, w.w, h[4*j4+3]);
        }
    }
    #pragma unroll
    for (int j = 0; j < 16; ++j) h[j] = fmaxf(h[j] * inv, 0.0f);

    float l0 = spb[0], l1 = spb[1];
    #pragma unroll
    for (int j = 0; j < 16; ++j) {
        l0 = fmaf(h[j], spw[2*j+0], l0);
        l1 = fmaf(h[j], spw[2*j+1], l1);
    }
    float m = fmaxf(l0, l1);
    float e0 = __expf(l0 - m), e1 = __expf(l1 - m);
    float r = fast_rcp(e0 + e1);
    float s0 = e0 * r, s1 = e1 * r;
    s_out[2*n+0] = s0;
    s_out[2*n+1] = s1;

    float w[32];
    #pragma unroll
    for (int j = 0; j < 16; ++j) { w[j] = s0 * h[j]; w[16+j] = s1 * h[j]; }

    int b = batch[n];
    int lane = threadIdx.x & 63;
    #pragma unroll
    for (int o = 1; o < 64; o <<= 1) {
        int bn = __shfl_down(b, o);
        bool take = (lane + o < 64) && (bn == b);
        #pragma unroll
        for (int cc = 0; cc < 32; ++cc) {
            float vn = __shfl_down(w[cc], o);
            if (take) w[cc] += vn;
        }
    }
    int bp = __shfl_up(b, 1);
    if (lane == 0 || bp != b) {
        float* pg = pooled + 32*b;
        #pragma unroll
        for (int cc = 0; cc < 32; ++cc) unsafeAtomicAdd(pg + cc, w[cc]);
    }
}

// ---------------------------------------------------------------------------
// K3: per-graph heads. z, recon, analytic potential + forces.
// ---------------------------------------------------------------------------
__global__ __launch_bounds__(256) void graph_kernel(
    const float* __restrict__ pooled,
    const float* __restrict__ toz_w, const float* __restrict__ toz_b,
    const float* __restrict__ vp_w1, const float* __restrict__ vp_b1,
    const float* __restrict__ vp_w2, const float* __restrict__ vp_b2,
    const float* __restrict__ bridge_w, const float* __restrict__ bridge_b,
    float* __restrict__ out_recon, float* __restrict__ out_z,
    float* __restrict__ out_forces, float* __restrict__ out_V)
{
    int g = blockIdx.x * 256 + threadIdx.x;
    if (g >= NUM_GRAPHS) return;

    const float* P = pooled + 32*g;
    float z[8];
    #pragma unroll
    for (int k = 0; k < 2; ++k) {
        #pragma unroll
        for (int d = 0; d < 4; ++d) {
            float a = toz_b[d];
            #pragma unroll
            for (int i = 0; i < 16; ++i) a = fmaf(P[16*k+i], toz_w[4*i+d], a);
            z[4*k+d] = a;
        }
    }
    #pragma unroll
    for (int i = 0; i < 8; ++i) out_z[8*g+i] = z[i];

    #pragma unroll
    for (int j = 0; j < 32; ++j) {
        float a = bridge_b[j];
        #pragma unroll
        for (int i = 0; i < 8; ++i) a = fmaf(z[i], bridge_w[32*i+j], a);
        out_recon[32*g+j] = a;
    }

    float d0 = z[0]-z[4], d1 = z[1]-z[5];
    float dd = sqrtf(d0*d0 + d1*d1 + 1e-6f);

    float V = vp_b2[0];
    float dV = 0.0f;
    #pragma unroll
    for (int j = 0; j < 32; ++j) {
        float w1 = vp_w1[j];
        float t  = fmaf(dd, w1, vp_b1[j]);
        float et = __expf(t);
        float sp = __logf(1.0f + et);
        float sg = et / (1.0f + et);
        float w2 = vp_w2[j];
        V  = fmaf(sp, w2, V);
        dV = fmaf(sg * w1, w2, dV);
    }
    out_V[g] = V;

    float scale = dV / dd;
    float gx = scale * d0, gy = scale * d1;
    out_forces[4*g+0] = -gx;
    out_forces[4*g+1] = -gy;
    out_forces[4*g+2] =  gx;
    out_forces[4*g+3] =  gy;
}

// ---------------------------------------------------------------------------
extern "C" void kernel_launch(void* const* d_in, const int* in_sizes, int n_in,
                              void* d_out, int out_size, void* d_ws, size_t ws_size,
                              hipStream_t stream) {
    const float* x        = (const float*)d_in[0];
    const float* pos      = (const float*)d_in[1];
    const int*   ei       = (const int*)  d_in[2];
    const int*   batch    = (const int*)  d_in[3];
    const float* enc_w1   = (const float*)d_in[4];
    const float* enc_b1   = (const float*)d_in[5];
    const float* enc_w2   = (const float*)d_in[6];
    const float* enc_b2   = (const float*)d_in[7];
    const float* pool_w   = (const float*)d_in[8];
    const float* pool_b   = (const float*)d_in[9];
    const float* toz_w    = (const float*)d_in[10];
    const float* toz_b    = (const float*)d_in[11];
    const float* vp_w1    = (const float*)d_in[12];
    const float* vp_b1    = (const float*)d_in[13];
    const float* vp_w2    = (const float*)d_in[14];
    const float* vp_b2    = (const float*)d_in[15];
    const float* bridge_w = (const float*)d_in[16];
    const float* bridge_b = (const float*)d_in[17];

    // workspace layout (4B units), ~26.1 MB total (within prior footprint)
    int*   cursor = (int*)d_ws;                              // 1024
    float* pooled = (float*)d_ws + NBIN;                     // 32768
    int*   staged = (int*)d_ws + NBIN + 32768;               // 1024*4608
    float* xp     = (float*)(staged + (size_t)NBIN*CAPB);    // 2097152

    float* out        = (float*)d_out;
    float* out_recon  = out;                        // 1024*32
    float* out_z      = out_recon + 1024*32;        // 1024*8
    float* out_s      = out_z + 1024*8;             // 262144*2
    float* out_forces = out_s + (size_t)N_NODES*2;  // 1024*4
    float* out_V      = out_forces + 1024*4;        // 1024

    hipMemsetAsync(d_ws, 0, (size_t)(NBIN + 32768) * sizeof(float), stream);

    pack_kernel   <<<N_NODES/256, 256, 0, stream>>>(x, pos, xp);
    binning_kernel<<<1024, 256, 0, stream>>>(ei, cursor, staged);
    fused_bucket_kernel<<<NBIN, 256, 0, stream>>>(
        xp, cursor, staged, batch,
        enc_w1, enc_b1, enc_w2, enc_b2, pool_w, pool_b, out_s, pooled);
    graph_kernel<<<NUM_GRAPHS/256, 256, 0, stream>>>(
        pooled, toz_w, toz_b, vp_w1, vp_b1, vp_w2, vp_b2,
        bridge_w, bridge_b, out_recon, out_z, out_forces, out_V);
}

// Round 3
// 422.552 us; speedup vs baseline: 1.4457x; 1.4457x over previous
//
#include <hip/hip_runtime.h>
#include <math.h>

#define N_NODES   262144
#define N_EDGES   4194304
#define NUM_GRAPHS 1024
#define NBIN      1024         // dst buckets (dst >> 8)
#define BNODE     256          // nodes per bucket
#define CAPB      4608         // fixed capacity per bucket (mean 4096, +8 sigma)

static __device__ __forceinline__ float fast_rcp(float v) {
    return __builtin_amdgcn_rcpf(v);
}

// ---------------------------------------------------------------------------
// K0: pack x (4f) + pos (3f) into one 32B record per node -> single 64B line
// per random src gather in the fused kernel.
// ---------------------------------------------------------------------------
__global__ __launch_bounds__(256) void pack_kernel(
    const float* __restrict__ x, const float* __restrict__ pos,
    float* __restrict__ xp)
{
    int n = blockIdx.x * 256 + threadIdx.x;
    float4 xv = *(const float4*)(x + 4*n);
    float px = pos[3*n+0], py = pos[3*n+1], pz = pos[3*n+2];
    float4* o = (float4*)(xp + 8*n);
    o[0] = xv;
    o[1] = make_float4(px, py, pz, 0.0f);
}

// ---------------------------------------------------------------------------
// K1: binning into fixed-stride buckets. 1024 blocks x 256 thr x 16 edges.
// Per-block LDS histogram -> one global cursor atomic per nonzero bin ->
// scatter packed (lo<<18)|src. src kept in registers (single ei pass).
// ---------------------------------------------------------------------------
__global__ __launch_bounds__(256) void binning_kernel(
    const int* __restrict__ ei, int* __restrict__ cursor,
    int* __restrict__ staged)
{
    __shared__ int cnt[NBIN];
    __shared__ int runbase[NBIN];
    #pragma unroll
    for (int t = 0; t < NBIN/256; ++t) cnt[t*256 + threadIdx.x] = 0;
    __syncthreads();

    int base = blockIdx.x * 4096;
    int ds[16], sr[16];
    #pragma unroll
    for (int i = 0; i < 16; ++i) {
        ds[i] = ei[N_EDGES + base + i*256 + threadIdx.x];
        sr[i] = ei[base + i*256 + threadIdx.x];
        atomicAdd(&cnt[ds[i] >> 8], 1);
    }
    __syncthreads();
    #pragma unroll
    for (int t = 0; t < NBIN/256; ++t) {
        int k = t*256 + threadIdx.x;
        int c = cnt[k];
        runbase[k] = c ? atomicAdd(cursor + k, c) : 0;
        cnt[k] = 0;
    }
    __syncthreads();
    #pragma unroll
    for (int i = 0; i < 16; ++i) {
        int dst = ds[i];
        int bk  = dst >> 8;
        int r   = atomicAdd(&cnt[bk], 1);
        int idx = runbase[bk] + r;
        if (idx < CAPB)                       // ~8-sigma guard, never in practice
            staged[bk*CAPB + idx] = ((dst & 255) << 18) | sr[i];
    }
}

// ---------------------------------------------------------------------------
// Per-edge contribution: rows 4..7 (x[src]) + row 8 (dist) of enc_w1, on top
// of the per-node precomputed hd[] (bias + dst rows). silu accumulate.
// ---------------------------------------------------------------------------
static __device__ __forceinline__ void edge_contrib(
    const float* __restrict__ sw1, const float* __restrict__ hd,
    float4 xs, float dist, float* __restrict__ acc)
{
    float h[16];
    #pragma unroll
    for (int j4 = 0; j4 < 4; ++j4) {
        float4 w = *(const float4*)&sw1[4*16 + 4*j4];
        h[4*j4+0] = fmaf(xs.x, w.x, hd[4*j4+0]);
        h[4*j4+1] = fmaf(xs.x, w.y, hd[4*j4+1]);
        h[4*j4+2] = fmaf(xs.x, w.z, hd[4*j4+2]);
        h[4*j4+3] = fmaf(xs.x, w.w, hd[4*j4+3]);
    }
    #pragma unroll
    for (int j4 = 0; j4 < 4; ++j4) {
        float4 w = *(const float4*)&sw1[5*16 + 4*j4];
        h[4*j4+0] = fmaf(xs.y, w.x, h[4*j4+0]);
        h[4*j4+1] = fmaf(xs.y, w.y, h[4*j4+1]);
        h[4*j4+2] = fmaf(xs.y, w.z, h[4*j4+2]);
        h[4*j4+3] = fmaf(xs.y, w.w, h[4*j4+3]);
    }
    #pragma unroll
    for (int j4 = 0; j4 < 4; ++j4) {
        float4 w = *(const float4*)&sw1[6*16 + 4*j4];
        h[4*j4+0] = fmaf(xs.z, w.x, h[4*j4+0]);
        h[4*j4+1] = fmaf(xs.z, w.y, h[4*j4+1]);
        h[4*j4+2] = fmaf(xs.z, w.z, h[4*j4+2]);
        h[4*j4+3] = fmaf(xs.z, w.w, h[4*j4+3]);
    }
    #pragma unroll
    for (int j4 = 0; j4 < 4; ++j4) {
        float4 w = *(const float4*)&sw1[7*16 + 4*j4];
        h[4*j4+0] = fmaf(xs.w, w.x, h[4*j4+0]);
        h[4*j4+1] = fmaf(xs.w, w.y, h[4*j4+1]);
        h[4*j4+2] = fmaf(xs.w, w.z, h[4*j4+2]);
        h[4*j4+3] = fmaf(xs.w, w.w, h[4*j4+3]);
    }
    #pragma unroll
    for (int j4 = 0; j4 < 4; ++j4) {
        float4 w = *(const float4*)&sw1[8*16 + 4*j4];
        h[4*j4+0] = fmaf(dist, w.x, h[4*j4+0]);
        h[4*j4+1] = fmaf(dist, w.y, h[4*j4+1]);
        h[4*j4+2] = fmaf(dist, w.z, h[4*j4+2]);
        h[4*j4+3] = fmaf(dist, w.w, h[4*j4+3]);
    }
    #pragma unroll
    for (int j = 0; j < 16; ++j) {
        float sg = fast_rcp(1.0f + __expf(-h[j]));
        acc[j] = fmaf(h[j], sg, acc[j]);
    }
}

// ---------------------------------------------------------------------------
// K2 (fused): one block per 256-node bucket.
// Phase A: LDS counting sort of the bucket's edges (deg hist -> shuffle scan
//          -> scatter src ids into esrc[]). staged read twice (2nd is L2-hot).
// Phase B: round-1-style per-node register loop: src ids from LDS, packed
//          xp gathers (1 line/edge), hoisted dst rows, 2-wide unroll.
// Phase C: node MLP + softmax + wave-segmented attention pooling.
// ---------------------------------------------------------------------------
__global__ __launch_bounds__(256, 6) void fused_node_kernel(
    const float* __restrict__ xp,
    const int* __restrict__ cursor, const int* __restrict__ staged,
    const int* __restrict__ batch,
    const float* __restrict__ w1, const float* __restrict__ b1,
    const float* __restrict__ w2, const float* __restrict__ b2,
    const float* __restrict__ pw, const float* __restrict__ pb,
    float* __restrict__ s_out, float* __restrict__ pooled)
{
    __shared__ int esrc[CAPB];                 // 18432 B
    __shared__ int ldeg[BNODE];
    __shared__ int lcur[BNODE];
    __shared__ int wsum[4];
    __shared__ __align__(16) float sw1[144];
    __shared__ float sb1[16];
    __shared__ __align__(16) float sw2[256];
    __shared__ float sb2[16];
    __shared__ float spw[32];
    __shared__ float spb[2];

    if (threadIdx.x < 144) sw1[threadIdx.x] = w1[threadIdx.x];
    if (threadIdx.x >= 144 && threadIdx.x < 160) sb1[threadIdx.x - 144] = b1[threadIdx.x - 144];
    if (threadIdx.x >= 160 && threadIdx.x < 176) sb2[threadIdx.x - 160] = b2[threadIdx.x - 160];
    if (threadIdx.x >= 176 && threadIdx.x < 208) spw[threadIdx.x - 176] = pw[threadIdx.x - 176];
    if (threadIdx.x >= 208 && threadIdx.x < 210) spb[threadIdx.x - 208] = pb[threadIdx.x - 208];
    sw2[threadIdx.x] = w2[threadIdx.x];
    ldeg[threadIdx.x] = 0;
    __syncthreads();

    int bkt  = blockIdx.x;
    int cnt  = cursor[bkt]; if (cnt > CAPB) cnt = CAPB;
    int base = bkt * CAPB;
    int nb0  = bkt * BNODE;

    // ---- Phase A: counting sort into LDS ----
    for (int i = threadIdx.x; i < cnt; i += 256)
        atomicAdd(&ldeg[staged[base + i] >> 18], 1);
    __syncthreads();

    int dg   = ldeg[threadIdx.x];              // degree of node nb0+tid
    int lane = threadIdx.x & 63, wid = threadIdx.x >> 6;
    int inc  = dg;
    #pragma unroll
    for (int o = 1; o < 64; o <<= 1) {
        int t = __shfl_up(inc, o);
        if (lane >= o) inc += t;
    }
    if (lane == 63) wsum[wid] = inc;
    __syncthreads();
    int wb = 0;
    #pragma unroll
    for (int w = 0; w < 4; ++w) if (w < wid) wb += wsum[w];
    int r0 = wb + inc - dg;                    // exclusive row offset in esrc
    lcur[threadIdx.x] = r0;
    __syncthreads();

    for (int i = threadIdx.x; i < cnt; i += 256) {
        int p  = staged[base + i];             // L2-hot re-read
        int lo = p >> 18;
        int r  = atomicAdd(&lcur[lo], 1);
        esrc[r] = p & 0x3FFFF;
    }
    __syncthreads();

    // ---- Phase B: per-node gather + edge MLP ----
    int n = nb0 + threadIdx.x;
    const float4* xp4 = (const float4*)xp;
    float4 xd = xp4[2*n];
    float4 pd = xp4[2*n+1];

    // hd[j] = b1[j] + sum_{i<4} xd_i * w1[i][j]  -- hoisted out of edge loop
    float hd[16];
    #pragma unroll
    for (int j = 0; j < 16; ++j) hd[j] = sb1[j];
    #pragma unroll
    for (int j4 = 0; j4 < 4; ++j4) {
        float4 w0 = *(const float4*)&sw1[0*16 + 4*j4];
        float4 w1r = *(const float4*)&sw1[1*16 + 4*j4];
        float4 w2r = *(const float4*)&sw1[2*16 + 4*j4];
        float4 w3r = *(const float4*)&sw1[3*16 + 4*j4];
        hd[4*j4+0] = fmaf(xd.x, w0.x, hd[4*j4+0]);
        hd[4*j4+1] = fmaf(xd.x, w0.y, hd[4*j4+1]);
        hd[4*j4+2] = fmaf(xd.x, w0.z, hd[4*j4+2]);
        hd[4*j4+3] = fmaf(xd.x, w0.w, hd[4*j4+3]);
        hd[4*j4+0] = fmaf(xd.y, w1r.x, hd[4*j4+0]);
        hd[4*j4+1] = fmaf(xd.y, w1r.y, hd[4*j4+1]);
        hd[4*j4+2] = fmaf(xd.y, w1r.z, hd[4*j4+2]);
        hd[4*j4+3] = fmaf(xd.y, w1r.w, hd[4*j4+3]);
        hd[4*j4+0] = fmaf(xd.z, w2r.x, hd[4*j4+0]);
        hd[4*j4+1] = fmaf(xd.z, w2r.y, hd[4*j4+1]);
        hd[4*j4+2] = fmaf(xd.z, w2r.z, hd[4*j4+2]);
        hd[4*j4+3] = fmaf(xd.z, w2r.w, hd[4*j4+3]);
        hd[4*j4+0] = fmaf(xd.w, w3r.x, hd[4*j4+0]);
        hd[4*j4+1] = fmaf(xd.w, w3r.y, hd[4*j4+1]);
        hd[4*j4+2] = fmaf(xd.w, w3r.z, hd[4*j4+2]);
        hd[4*j4+3] = fmaf(xd.w, w3r.w, hd[4*j4+3]);
    }

    float acc[16];
    #pragma unroll
    for (int j = 0; j < 16; ++j) acc[j] = 0.0f;

    int k = 0;
    for (; k + 2 <= dg; k += 2) {
        int s0 = esrc[r0 + k];
        int s1 = esrc[r0 + k + 1];
        float4 a0 = xp4[2*s0], p0 = xp4[2*s0+1];
        float4 a1 = xp4[2*s1], p1 = xp4[2*s1+1];

        float dx0 = p0.x - pd.x, dy0 = p0.y - pd.y, dz0 = p0.z - pd.z;
        float dist0 = sqrtf(fmaf(dx0, dx0, fmaf(dy0, dy0, dz0*dz0)));
        edge_contrib(sw1, hd, a0, dist0, acc);

        float dx1 = p1.x - pd.x, dy1 = p1.y - pd.y, dz1 = p1.z - pd.z;
        float dist1 = sqrtf(fmaf(dx1, dx1, fmaf(dy1, dy1, dz1*dz1)));
        edge_contrib(sw1, hd, a1, dist1, acc);
    }
    if (k < dg) {
        int s0 = esrc[r0 + k];
        float4 a0 = xp4[2*s0], p0 = xp4[2*s0+1];
        float dx0 = p0.x - pd.x, dy0 = p0.y - pd.y, dz0 = p0.z - pd.z;
        float dist0 = sqrtf(fmaf(dx0, dx0, fmaf(dy0, dy0, dz0*dz0)));
        edge_contrib(sw1, hd, a0, dist0, acc);
    }

    // ---- Phase C: node MLP + softmax + pooling ----
    float c = (float)dg;
    float inv = fast_rcp(fmaxf(c, 1.0f));
    float h[16];
    #pragma unroll
    for (int j = 0; j < 16; ++j) h[j] = c * sb2[j];
    #pragma unroll
    for (int i = 0; i < 16; ++i) {
        float f = acc[i];
        #pragma unroll
        for (int j4 = 0; j4 < 4; ++j4) {
            float4 w = *(const float4*)&sw2[i*16 + 4*j4];
            h[4*j4+0] = fmaf(f, w.x, h[4*j4+0]);
            h[4*j4+1] = fmaf(f, w.y, h[4*j4+1]);
            h[4*j4+2] = fmaf(f, w.z, h[4*j4+2]);
            h[4*j4+3] = fmaf(f, w.w, h[4*j4+3]);
        }
    }
    #pragma unroll
    for (int j = 0; j < 16; ++j) h[j] = fmaxf(h[j] * inv, 0.0f);

    float l0 = spb[0], l1 = spb[1];
    #pragma unroll
    for (int j = 0; j < 16; ++j) {
        l0 = fmaf(h[j], spw[2*j+0], l0);
        l1 = fmaf(h[j], spw[2*j+1], l1);
    }
    float m = fmaxf(l0, l1);
    float e0 = __expf(l0 - m), e1 = __expf(l1 - m);
    float r = fast_rcp(e0 + e1);
    float s0 = e0 * r, s1 = e1 * r;
    s_out[2*n+0] = s0;
    s_out[2*n+1] = s1;

    float w[32];
    #pragma unroll
    for (int j = 0; j < 16; ++j) { w[j] = s0 * h[j]; w[16+j] = s1 * h[j]; }

    int b = batch[n];
    #pragma unroll
    for (int o = 1; o < 64; o <<= 1) {
        int bn = __shfl_down(b, o);
        bool take = (lane + o < 64) && (bn == b);
        #pragma unroll
        for (int cc = 0; cc < 32; ++cc) {
            float vn = __shfl_down(w[cc], o);
            if (take) w[cc] += vn;
        }
    }
    int bp = __shfl_up(b, 1);
    if (lane == 0 || bp != b) {
        float* pg = pooled + 32*b;
        #pragma unroll
        for (int cc = 0; cc < 32; ++cc) unsafeAtomicAdd(pg + cc, w[cc]);
    }
}

// ---------------------------------------------------------------------------
// K3: per-graph heads. z, recon, analytic potential + forces.
// ---------------------------------------------------------------------------
__global__ __launch_bounds__(256) void graph_kernel(
    const float* __restrict__ pooled,
    const float* __restrict__ toz_w, const float* __restrict__ toz_b,
    const float* __restrict__ vp_w1, const float* __restrict__ vp_b1,
    const float* __restrict__ vp_w2, const float* __restrict__ vp_b2,
    const float* __restrict__ bridge_w, const float* __restrict__ bridge_b,
    float* __restrict__ out_recon, float* __restrict__ out_z,
    float* __restrict__ out_forces, float* __restrict__ out_V)
{
    int g = blockIdx.x * 256 + threadIdx.x;
    if (g >= NUM_GRAPHS) return;

    const float* P = pooled + 32*g;
    float z[8];
    #pragma unroll
    for (int k = 0; k < 2; ++k) {
        #pragma unroll
        for (int d = 0; d < 4; ++d) {
            float a = toz_b[d];
            #pragma unroll
            for (int i = 0; i < 16; ++i) a = fmaf(P[16*k+i], toz_w[4*i+d], a);
            z[4*k+d] = a;
        }
    }
    #pragma unroll
    for (int i = 0; i < 8; ++i) out_z[8*g+i] = z[i];

    #pragma unroll
    for (int j = 0; j < 32; ++j) {
        float a = bridge_b[j];
        #pragma unroll
        for (int i = 0; i < 8; ++i) a = fmaf(z[i], bridge_w[32*i+j], a);
        out_recon[32*g+j] = a;
    }

    float d0 = z[0]-z[4], d1 = z[1]-z[5];
    float dd = sqrtf(d0*d0 + d1*d1 + 1e-6f);

    float V = vp_b2[0];
    float dV = 0.0f;
    #pragma unroll
    for (int j = 0; j < 32; ++j) {
        float w1 = vp_w1[j];
        float t  = fmaf(dd, w1, vp_b1[j]);
        float et = __expf(t);
        float sp = __logf(1.0f + et);
        float sg = et / (1.0f + et);
        float w2 = vp_w2[j];
        V  = fmaf(sp, w2, V);
        dV = fmaf(sg * w1, w2, dV);
    }
    out_V[g] = V;

    float scale = dV / dd;
    float gx = scale * d0, gy = scale * d1;
    out_forces[4*g+0] = -gx;
    out_forces[4*g+1] = -gy;
    out_forces[4*g+2] =  gx;
    out_forces[4*g+3] =  gy;
}

// ---------------------------------------------------------------------------
extern "C" void kernel_launch(void* const* d_in, const int* in_sizes, int n_in,
                              void* d_out, int out_size, void* d_ws, size_t ws_size,
                              hipStream_t stream) {
    const float* x        = (const float*)d_in[0];
    const float* pos      = (const float*)d_in[1];
    const int*   ei       = (const int*)  d_in[2];
    const int*   batch    = (const int*)  d_in[3];
    const float* enc_w1   = (const float*)d_in[4];
    const float* enc_b1   = (const float*)d_in[5];
    const float* enc_w2   = (const float*)d_in[6];
    const float* enc_b2   = (const float*)d_in[7];
    const float* pool_w   = (const float*)d_in[8];
    const float* pool_b   = (const float*)d_in[9];
    const float* toz_w    = (const float*)d_in[10];
    const float* toz_b    = (const float*)d_in[11];
    const float* vp_w1    = (const float*)d_in[12];
    const float* vp_b1    = (const float*)d_in[13];
    const float* vp_w2    = (const float*)d_in[14];
    const float* vp_b2    = (const float*)d_in[15];
    const float* bridge_w = (const float*)d_in[16];
    const float* bridge_b = (const float*)d_in[17];

    // workspace layout (4B units), ~27.4 MB
    int*   cursor = (int*)d_ws;                              // 1024
    float* pooled = (float*)d_ws + NBIN;                     // 32768
    int*   staged = (int*)d_ws + NBIN + 32768;               // 1024*4608
    float* xp     = (float*)(staged + (size_t)NBIN*CAPB);    // 2097152

    float* out        = (float*)d_out;
    float* out_recon  = out;                        // 1024*32
    float* out_z      = out_recon + 1024*32;        // 1024*8
    float* out_s      = out_z + 1024*8;             // 262144*2
    float* out_forces = out_s + (size_t)N_NODES*2;  // 1024*4
    float* out_V      = out_forces + 1024*4;        // 1024

    hipMemsetAsync(d_ws, 0, (size_t)(NBIN + 32768) * sizeof(float), stream);

    pack_kernel   <<<N_NODES/256, 256, 0, stream>>>(x, pos, xp);
    binning_kernel<<<1024, 256, 0, stream>>>(ei, cursor, staged);
    fused_node_kernel<<<NBIN, 256, 0, stream>>>(
        xp, cursor, staged, batch,
        enc_w1, enc_b1, enc_w2, enc_b2, pool_w, pool_b, out_s, pooled);
    graph_kernel<<<NUM_GRAPHS/256, 256, 0, stream>>>(
        pooled, toz_w, toz_b, vp_w1, vp_b1, vp_w2, vp_b2,
        bridge_w, bridge_b, out_recon, out_z, out_forces, out_V);
}

// Round 4
// 283.299 us; speedup vs baseline: 2.1563x; 1.4915x over previous
//
#include <hip/hip_runtime.h>
#include <math.h>

#define N_NODES   262144
#define N_EDGES   4194304
#define NUM_GRAPHS 1024
#define NBIN      1024         // dst buckets (dst >> 8)
#define BNODE     256          // nodes per bucket
#define CAPB      4608         // fixed capacity per bucket (mean 4096, +8 sigma)

static __device__ __forceinline__ float fast_rcp(float v) {
    return __builtin_amdgcn_rcpf(v);
}

// ---------------------------------------------------------------------------
// K0: pack x (4f) + pos (3f) into one 32B record per node -> single 64B line
// per random src gather in the fused kernel.
// ---------------------------------------------------------------------------
__global__ __launch_bounds__(256) void pack_kernel(
    const float* __restrict__ x, const float* __restrict__ pos,
    float* __restrict__ xp)
{
    int n = blockIdx.x * 256 + threadIdx.x;
    float4 xv = *(const float4*)(x + 4*n);
    float px = pos[3*n+0], py = pos[3*n+1], pz = pos[3*n+2];
    float4* o = (float4*)(xp + 8*n);
    o[0] = xv;
    o[1] = make_float4(px, py, pz, 0.0f);
}

// ---------------------------------------------------------------------------
// K1: binning into fixed-stride buckets. 1024 blocks x 256 thr x 16 edges.
// Per-block LDS histogram -> one global cursor atomic per nonzero bin ->
// scatter packed (lo<<18)|src. src kept in registers (single ei pass).
// ---------------------------------------------------------------------------
__global__ __launch_bounds__(256) void binning_kernel(
    const int* __restrict__ ei, int* __restrict__ cursor,
    int* __restrict__ staged)
{
    __shared__ int cnt[NBIN];
    __shared__ int runbase[NBIN];
    #pragma unroll
    for (int t = 0; t < NBIN/256; ++t) cnt[t*256 + threadIdx.x] = 0;
    __syncthreads();

    int base = blockIdx.x * 4096;
    int ds[16], sr[16];
    #pragma unroll
    for (int i = 0; i < 16; ++i) {
        ds[i] = ei[N_EDGES + base + i*256 + threadIdx.x];
        sr[i] = ei[base + i*256 + threadIdx.x];
        atomicAdd(&cnt[ds[i] >> 8], 1);
    }
    __syncthreads();
    #pragma unroll
    for (int t = 0; t < NBIN/256; ++t) {
        int k = t*256 + threadIdx.x;
        int c = cnt[k];
        runbase[k] = c ? atomicAdd(cursor + k, c) : 0;
        cnt[k] = 0;
    }
    __syncthreads();
    #pragma unroll
    for (int i = 0; i < 16; ++i) {
        int dst = ds[i];
        int bk  = dst >> 8;
        int r   = atomicAdd(&cnt[bk], 1);
        int idx = runbase[bk] + r;
        if (idx < CAPB)                       // ~8-sigma guard, never in practice
            staged[bk*CAPB + idx] = ((dst & 255) << 18) | sr[i];
    }
}

// ---------------------------------------------------------------------------
// Per-edge contribution: rows 4..7 (x[src]) + row 8 (dist) of enc_w1, on top
// of the per-node precomputed hd[] (bias + dst rows). silu accumulate.
// ---------------------------------------------------------------------------
static __device__ __forceinline__ void edge_contrib(
    const float* __restrict__ sw1, const float* __restrict__ hd,
    float4 xs, float dist, float* __restrict__ acc)
{
    float h[16];
    #pragma unroll
    for (int j4 = 0; j4 < 4; ++j4) {
        float4 w = *(const float4*)&sw1[4*16 + 4*j4];
        h[4*j4+0] = fmaf(xs.x, w.x, hd[4*j4+0]);
        h[4*j4+1] = fmaf(xs.x, w.y, hd[4*j4+1]);
        h[4*j4+2] = fmaf(xs.x, w.z, hd[4*j4+2]);
        h[4*j4+3] = fmaf(xs.x, w.w, hd[4*j4+3]);
    }
    #pragma unroll
    for (int j4 = 0; j4 < 4; ++j4) {
        float4 w = *(const float4*)&sw1[5*16 + 4*j4];
        h[4*j4+0] = fmaf(xs.y, w.x, h[4*j4+0]);
        h[4*j4+1] = fmaf(xs.y, w.y, h[4*j4+1]);
        h[4*j4+2] = fmaf(xs.y, w.z, h[4*j4+2]);
        h[4*j4+3] = fmaf(xs.y, w.w, h[4*j4+3]);
    }
    #pragma unroll
    for (int j4 = 0; j4 < 4; ++j4) {
        float4 w = *(const float4*)&sw1[6*16 + 4*j4];
        h[4*j4+0] = fmaf(xs.z, w.x, h[4*j4+0]);
        h[4*j4+1] = fmaf(xs.z, w.y, h[4*j4+1]);
        h[4*j4+2] = fmaf(xs.z, w.z, h[4*j4+2]);
        h[4*j4+3] = fmaf(xs.z, w.w, h[4*j4+3]);
    }
    #pragma unroll
    for (int j4 = 0; j4 < 4; ++j4) {
        float4 w = *(const float4*)&sw1[7*16 + 4*j4];
        h[4*j4+0] = fmaf(xs.w, w.x, h[4*j4+0]);
        h[4*j4+1] = fmaf(xs.w, w.y, h[4*j4+1]);
        h[4*j4+2] = fmaf(xs.w, w.z, h[4*j4+2]);
        h[4*j4+3] = fmaf(xs.w, w.w, h[4*j4+3]);
    }
    #pragma unroll
    for (int j4 = 0; j4 < 4; ++j4) {
        float4 w = *(const float4*)&sw1[8*16 + 4*j4];
        h[4*j4+0] = fmaf(dist, w.x, h[4*j4+0]);
        h[4*j4+1] = fmaf(dist, w.y, h[4*j4+1]);
        h[4*j4+2] = fmaf(dist, w.z, h[4*j4+2]);
        h[4*j4+3] = fmaf(dist, w.w, h[4*j4+3]);
    }
    #pragma unroll
    for (int j = 0; j < 16; ++j) {
        float sg = fast_rcp(1.0f + __expf(-h[j]));
        acc[j] = fmaf(h[j], sg, acc[j]);
    }
}

// ---------------------------------------------------------------------------
// K2 (fused): one block per 256-node bucket.
// Phase A: LDS counting sort of the bucket's edges (deg hist -> shuffle scan
//          -> scatter src ids into esrc[]). staged read twice (2nd is L2-hot).
// Phase B: per-node register loop: src ids from LDS, packed xp gathers
//          (1 line/edge), hoisted dst rows, 2-wide unroll.
// Phase C: node MLP + softmax + wave-segmented attention pooling.
// NOTE: launch_bounds (256,4) -- (256,6) forced VGPR=40 and spilled the
// register state to scratch (+475MB FETCH, +76MB WRITE in round 3).
// ---------------------------------------------------------------------------
__global__ __launch_bounds__(256, 4) void fused_node_kernel(
    const float* __restrict__ xp,
    const int* __restrict__ cursor, const int* __restrict__ staged,
    const int* __restrict__ batch,
    const float* __restrict__ w1, const float* __restrict__ b1,
    const float* __restrict__ w2, const float* __restrict__ b2,
    const float* __restrict__ pw, const float* __restrict__ pb,
    float* __restrict__ s_out, float* __restrict__ pooled)
{
    __shared__ int esrc[CAPB];                 // 18432 B
    __shared__ int ldeg[BNODE];
    __shared__ int lcur[BNODE];
    __shared__ int wsum[4];
    __shared__ __align__(16) float sw1[144];
    __shared__ float sb1[16];
    __shared__ __align__(16) float sw2[256];
    __shared__ float sb2[16];
    __shared__ float spw[32];
    __shared__ float spb[2];

    if (threadIdx.x < 144) sw1[threadIdx.x] = w1[threadIdx.x];
    if (threadIdx.x >= 144 && threadIdx.x < 160) sb1[threadIdx.x - 144] = b1[threadIdx.x - 144];
    if (threadIdx.x >= 160 && threadIdx.x < 176) sb2[threadIdx.x - 160] = b2[threadIdx.x - 160];
    if (threadIdx.x >= 176 && threadIdx.x < 208) spw[threadIdx.x - 176] = pw[threadIdx.x - 176];
    if (threadIdx.x >= 208 && threadIdx.x < 210) spb[threadIdx.x - 208] = pb[threadIdx.x - 208];
    sw2[threadIdx.x] = w2[threadIdx.x];
    ldeg[threadIdx.x] = 0;
    __syncthreads();

    int bkt  = blockIdx.x;
    int cnt  = cursor[bkt]; if (cnt > CAPB) cnt = CAPB;
    int base = bkt * CAPB;
    int nb0  = bkt * BNODE;

    // ---- Phase A: counting sort into LDS ----
    for (int i = threadIdx.x; i < cnt; i += 256)
        atomicAdd(&ldeg[staged[base + i] >> 18], 1);
    __syncthreads();

    int dg   = ldeg[threadIdx.x];              // degree of node nb0+tid
    int lane = threadIdx.x & 63, wid = threadIdx.x >> 6;
    int inc  = dg;
    #pragma unroll
    for (int o = 1; o < 64; o <<= 1) {
        int t = __shfl_up(inc, o);
        if (lane >= o) inc += t;
    }
    if (lane == 63) wsum[wid] = inc;
    __syncthreads();
    int wb = 0;
    #pragma unroll
    for (int w = 0; w < 4; ++w) if (w < wid) wb += wsum[w];
    int r0 = wb + inc - dg;                    // exclusive row offset in esrc
    lcur[threadIdx.x] = r0;
    __syncthreads();

    for (int i = threadIdx.x; i < cnt; i += 256) {
        int p  = staged[base + i];             // L2-hot re-read
        int lo = p >> 18;
        int r  = atomicAdd(&lcur[lo], 1);
        esrc[r] = p & 0x3FFFF;
    }
    __syncthreads();

    // ---- Phase B: per-node gather + edge MLP ----
    int n = nb0 + threadIdx.x;
    const float4* xp4 = (const float4*)xp;
    float4 xd = xp4[2*n];
    float4 pd = xp4[2*n+1];

    // hd[j] = b1[j] + sum_{i<4} xd_i * w1[i][j]  -- hoisted out of edge loop
    float hd[16];
    #pragma unroll
    for (int j = 0; j < 16; ++j) hd[j] = sb1[j];
    #pragma unroll
    for (int j4 = 0; j4 < 4; ++j4) {
        float4 w0 = *(const float4*)&sw1[0*16 + 4*j4];
        float4 w1r = *(const float4*)&sw1[1*16 + 4*j4];
        float4 w2r = *(const float4*)&sw1[2*16 + 4*j4];
        float4 w3r = *(const float4*)&sw1[3*16 + 4*j4];
        hd[4*j4+0] = fmaf(xd.x, w0.x, hd[4*j4+0]);
        hd[4*j4+1] = fmaf(xd.x, w0.y, hd[4*j4+1]);
        hd[4*j4+2] = fmaf(xd.x, w0.z, hd[4*j4+2]);
        hd[4*j4+3] = fmaf(xd.x, w0.w, hd[4*j4+3]);
        hd[4*j4+0] = fmaf(xd.y, w1r.x, hd[4*j4+0]);
        hd[4*j4+1] = fmaf(xd.y, w1r.y, hd[4*j4+1]);
        hd[4*j4+2] = fmaf(xd.y, w1r.z, hd[4*j4+2]);
        hd[4*j4+3] = fmaf(xd.y, w1r.w, hd[4*j4+3]);
        hd[4*j4+0] = fmaf(xd.z, w2r.x, hd[4*j4+0]);
        hd[4*j4+1] = fmaf(xd.z, w2r.y, hd[4*j4+1]);
        hd[4*j4+2] = fmaf(xd.z, w2r.z, hd[4*j4+2]);
        hd[4*j4+3] = fmaf(xd.z, w2r.w, hd[4*j4+3]);
        hd[4*j4+0] = fmaf(xd.w, w3r.x, hd[4*j4+0]);
        hd[4*j4+1] = fmaf(xd.w, w3r.y, hd[4*j4+1]);
        hd[4*j4+2] = fmaf(xd.w, w3r.z, hd[4*j4+2]);
        hd[4*j4+3] = fmaf(xd.w, w3r.w, hd[4*j4+3]);
    }

    float acc[16];
    #pragma unroll
    for (int j = 0; j < 16; ++j) acc[j] = 0.0f;

    int k = 0;
    for (; k + 2 <= dg; k += 2) {
        int s0 = esrc[r0 + k];
        int s1 = esrc[r0 + k + 1];
        float4 a0 = xp4[2*s0], p0 = xp4[2*s0+1];
        float4 a1 = xp4[2*s1], p1 = xp4[2*s1+1];

        float dx0 = p0.x - pd.x, dy0 = p0.y - pd.y, dz0 = p0.z - pd.z;
        float dist0 = sqrtf(fmaf(dx0, dx0, fmaf(dy0, dy0, dz0*dz0)));
        edge_contrib(sw1, hd, a0, dist0, acc);

        float dx1 = p1.x - pd.x, dy1 = p1.y - pd.y, dz1 = p1.z - pd.z;
        float dist1 = sqrtf(fmaf(dx1, dx1, fmaf(dy1, dy1, dz1*dz1)));
        edge_contrib(sw1, hd, a1, dist1, acc);
    }
    if (k < dg) {
        int s0 = esrc[r0 + k];
        float4 a0 = xp4[2*s0], p0 = xp4[2*s0+1];
        float dx0 = p0.x - pd.x, dy0 = p0.y - pd.y, dz0 = p0.z - pd.z;
        float dist0 = sqrtf(fmaf(dx0, dx0, fmaf(dy0, dy0, dz0*dz0)));
        edge_contrib(sw1, hd, a0, dist0, acc);
    }

    // ---- Phase C: node MLP + softmax + pooling ----
    float c = (float)dg;
    float inv = fast_rcp(fmaxf(c, 1.0f));
    float h[16];
    #pragma unroll
    for (int j = 0; j < 16; ++j) h[j] = c * sb2[j];
    #pragma unroll
    for (int i = 0; i < 16; ++i) {
        float f = acc[i];
        #pragma unroll
        for (int j4 = 0; j4 < 4; ++j4) {
            float4 w = *(const float4*)&sw2[i*16 + 4*j4];
            h[4*j4+0] = fmaf(f, w.x, h[4*j4+0]);
            h[4*j4+1] = fmaf(f, w.y, h[4*j4+1]);
            h[4*j4+2] = fmaf(f, w.z, h[4*j4+2]);
            h[4*j4+3] = fmaf(f, w.w, h[4*j4+3]);
        }
    }
    #pragma unroll
    for (int j = 0; j < 16; ++j) h[j] = fmaxf(h[j] * inv, 0.0f);

    float l0 = spb[0], l1 = spb[1];
    #pragma unroll
    for (int j = 0; j < 16; ++j) {
        l0 = fmaf(h[j], spw[2*j+0], l0);
        l1 = fmaf(h[j], spw[2*j+1], l1);
    }
    float m = fmaxf(l0, l1);
    float e0 = __expf(l0 - m), e1 = __expf(l1 - m);
    float r = fast_rcp(e0 + e1);
    float s0 = e0 * r, s1 = e1 * r;
    s_out[2*n+0] = s0;
    s_out[2*n+1] = s1;

    float w[32];
    #pragma unroll
    for (int j = 0; j < 16; ++j) { w[j] = s0 * h[j]; w[16+j] = s1 * h[j]; }

    int b = batch[n];
    #pragma unroll
    for (int o = 1; o < 64; o <<= 1) {
        int bn = __shfl_down(b, o);
        bool take = (lane + o < 64) && (bn == b);
        #pragma unroll
        for (int cc = 0; cc < 32; ++cc) {
            float vn = __shfl_down(w[cc], o);
            if (take) w[cc] += vn;
        }
    }
    int bp = __shfl_up(b, 1);
    if (lane == 0 || bp != b) {
        float* pg = pooled + 32*b;
        #pragma unroll
        for (int cc = 0; cc < 32; ++cc) unsafeAtomicAdd(pg + cc, w[cc]);
    }
}

// ---------------------------------------------------------------------------
// K3: per-graph heads. z, recon, analytic potential + forces.
// ---------------------------------------------------------------------------
__global__ __launch_bounds__(256) void graph_kernel(
    const float* __restrict__ pooled,
    const float* __restrict__ toz_w, const float* __restrict__ toz_b,
    const float* __restrict__ vp_w1, const float* __restrict__ vp_b1,
    const float* __restrict__ vp_w2, const float* __restrict__ vp_b2,
    const float* __restrict__ bridge_w, const float* __restrict__ bridge_b,
    float* __restrict__ out_recon, float* __restrict__ out_z,
    float* __restrict__ out_forces, float* __restrict__ out_V)
{
    int g = blockIdx.x * 256 + threadIdx.x;
    if (g >= NUM_GRAPHS) return;

    const float* P = pooled + 32*g;
    float z[8];
    #pragma unroll
    for (int k = 0; k < 2; ++k) {
        #pragma unroll
        for (int d = 0; d < 4; ++d) {
            float a = toz_b[d];
            #pragma unroll
            for (int i = 0; i < 16; ++i) a = fmaf(P[16*k+i], toz_w[4*i+d], a);
            z[4*k+d] = a;
        }
    }
    #pragma unroll
    for (int i = 0; i < 8; ++i) out_z[8*g+i] = z[i];

    #pragma unroll
    for (int j = 0; j < 32; ++j) {
        float a = bridge_b[j];
        #pragma unroll
        for (int i = 0; i < 8; ++i) a = fmaf(z[i], bridge_w[32*i+j], a);
        out_recon[32*g+j] = a;
    }

    float d0 = z[0]-z[4], d1 = z[1]-z[5];
    float dd = sqrtf(d0*d0 + d1*d1 + 1e-6f);

    float V = vp_b2[0];
    float dV = 0.0f;
    #pragma unroll
    for (int j = 0; j < 32; ++j) {
        float w1 = vp_w1[j];
        float t  = fmaf(dd, w1, vp_b1[j]);
        float et = __expf(t);
        float sp = __logf(1.0f + et);
        float sg = et / (1.0f + et);
        float w2 = vp_w2[j];
        V  = fmaf(sp, w2, V);
        dV = fmaf(sg * w1, w2, dV);
    }
    out_V[g] = V;

    float scale = dV / dd;
    float gx = scale * d0, gy = scale * d1;
    out_forces[4*g+0] = -gx;
    out_forces[4*g+1] = -gy;
    out_forces[4*g+2] =  gx;
    out_forces[4*g+3] =  gy;
}

// ---------------------------------------------------------------------------
extern "C" void kernel_launch(void* const* d_in, const int* in_sizes, int n_in,
                              void* d_out, int out_size, void* d_ws, size_t ws_size,
                              hipStream_t stream) {
    const float* x        = (const float*)d_in[0];
    const float* pos      = (const float*)d_in[1];
    const int*   ei       = (const int*)  d_in[2];
    const int*   batch    = (const int*)  d_in[3];
    const float* enc_w1   = (const float*)d_in[4];
    const float* enc_b1   = (const float*)d_in[5];
    const float* enc_w2   = (const float*)d_in[6];
    const float* enc_b2   = (const float*)d_in[7];
    const float* pool_w   = (const float*)d_in[8];
    const float* pool_b   = (const float*)d_in[9];
    const float* toz_w    = (const float*)d_in[10];
    const float* toz_b    = (const float*)d_in[11];
    const float* vp_w1    = (const float*)d_in[12];
    const float* vp_b1    = (const float*)d_in[13];
    const float* vp_w2    = (const float*)d_in[14];
    const float* vp_b2    = (const float*)d_in[15];
    const float* bridge_w = (const float*)d_in[16];
    const float* bridge_b = (const float*)d_in[17];

    // workspace layout (4B units), ~27.4 MB
    int*   cursor = (int*)d_ws;                              // 1024
    float* pooled = (float*)d_ws + NBIN;                     // 32768
    int*   staged = (int*)d_ws + NBIN + 32768;               // 1024*4608
    float* xp     = (float*)(staged + (size_t)NBIN*CAPB);    // 2097152

    float* out        = (float*)d_out;
    float* out_recon  = out;                        // 1024*32
    float* out_z      = out_recon + 1024*32;        // 1024*8
    float* out_s      = out_z + 1024*8;             // 262144*2
    float* out_forces = out_s + (size_t)N_NODES*2;  // 1024*4
    float* out_V      = out_forces + 1024*4;        // 1024

    hipMemsetAsync(d_ws, 0, (size_t)(NBIN + 32768) * sizeof(float), stream);

    pack_kernel   <<<N_NODES/256, 256, 0, stream>>>(x, pos, xp);
    binning_kernel<<<1024, 256, 0, stream>>>(ei, cursor, staged);
    fused_node_kernel<<<NBIN, 256, 0, stream>>>(
        xp, cursor, staged, batch,
        enc_w1, enc_b1, enc_w2, enc_b2, pool_w, pool_b, out_s, pooled);
    graph_kernel<<<NUM_GRAPHS/256, 256, 0, stream>>>(
        pooled, toz_w, toz_b, vp_w1, vp_b1, vp_w2, vp_b2,
        bridge_w, bridge_b, out_recon, out_z, out_forces, out_V);
}